// Round 3
// baseline (525.361 us; speedup 1.0000x reference)
//
#include <hip/hip_runtime.h>
#include <hip/hip_bf16.h>

typedef __bf16 bf16;
typedef __attribute__((ext_vector_type(8))) __bf16 bf16x8;
typedef __attribute__((ext_vector_type(4))) float floatx4;

#define MFMA_16x16x32(a, b, c) __builtin_amdgcn_mfma_f32_16x16x32_bf16((a), (b), (c), 0, 0, 0)

// load 8 consecutive elements as bf16x8, converting if source is fp32
__device__ __forceinline__ bf16x8 load8(const bf16* p) {
  return *(const bf16x8*)p;
}
__device__ __forceinline__ bf16x8 load8(const float* p) {
  floatx4 a = *(const floatx4*)p;
  floatx4 b = *(const floatx4*)(p + 4);
  bf16x8 r;
  r[0] = (bf16)a[0]; r[1] = (bf16)a[1]; r[2] = (bf16)a[2]; r[3] = (bf16)a[3];
  r[4] = (bf16)b[0]; r[5] = (bf16)b[1]; r[6] = (bf16)b[2]; r[7] = (bf16)b[3];
  return r;
}

// ---------------------------------------------------------------------------
// GEMM: C[M,N] = A[M,K] @ W[N,K]^T + bias, M=8192, N=1024, K=1024.
// A: fp32 or bf16; W: fp32; bias: fp32; C: bf16 (ws) or fp32 (final out).
// 128x128 tile, BK=64, 256 threads = 4 waves, each wave 64x64 (4x4 MFMA).
// Register-mediated staging (global->reg(cvt bf16)->LDS), padded stride 72.
// ---------------------------------------------------------------------------
template <typename AT, typename CT>
__device__ __forceinline__ void gemm128_body(
    const AT* __restrict__ A, const float* __restrict__ W,
    const float* __restrict__ bias, CT* __restrict__ C)
{
  constexpr int Kdim = 1024;
  constexpr int LDP = 72;  // padded LDS row stride (elements)
  __shared__ __align__(16) bf16 As[128 * LDP];
  __shared__ __align__(16) bf16 Bs[128 * LDP];

  const int tid  = threadIdx.x;
  const int lane = tid & 63;
  const int wave = tid >> 6;
  const int quad = lane >> 4;
  const int l15  = lane & 15;

  const int gm0   = blockIdx.y * 128;
  const int gn0   = blockIdx.x * 128;
  const int m_off = (wave >> 1) * 64;
  const int n_off = (wave & 1) * 64;

  floatx4 acc[4][4] = {};

  int srow[4], scol[4];
  #pragma unroll
  for (int i = 0; i < 4; ++i) {
    int c = i * 256 + tid;
    srow[i] = c >> 3;        // tile row 0..127
    scol[i] = (c & 7) * 8;   // element col 0,8,...,56
  }

  for (int kt = 0; kt < Kdim / 64; ++kt) {
    // global loads into registers (converted to bf16; overlap with prev MFMA)
    bf16x8 ar[4], br[4];
    #pragma unroll
    for (int i = 0; i < 4; ++i) {
      ar[i] = load8(A + (size_t)(gm0 + srow[i]) * Kdim + kt * 64 + scol[i]);
      br[i] = load8(W + (size_t)(gn0 + srow[i]) * Kdim + kt * 64 + scol[i]);
    }
    __syncthreads();  // previous iteration's fragment reads complete
    #pragma unroll
    for (int i = 0; i < 4; ++i) {
      *(bf16x8*)&As[srow[i] * LDP + scol[i]] = ar[i];
      *(bf16x8*)&Bs[srow[i] * LDP + scol[i]] = br[i];
    }
    __syncthreads();  // tiles visible

    #pragma unroll
    for (int kk = 0; kk < 2; ++kk) {
      bf16x8 af[4], bfr[4];
      #pragma unroll
      for (int i = 0; i < 4; ++i) {
        af[i]  = *(const bf16x8*)&As[(m_off + i * 16 + l15) * LDP + (kk * 4 + quad) * 8];
        bfr[i] = *(const bf16x8*)&Bs[(n_off + i * 16 + l15) * LDP + (kk * 4 + quad) * 8];
      }
      #pragma unroll
      for (int i = 0; i < 4; ++i)
        #pragma unroll
        for (int j = 0; j < 4; ++j)
          acc[i][j] = MFMA_16x16x32(af[i], bfr[j], acc[i][j]);
    }
  }

  // epilogue: C/D layout col = lane&15, row = quad*4 + reg (m89/m91 verified)
  #pragma unroll
  for (int j = 0; j < 4; ++j) {
    const int gcol = gn0 + n_off + j * 16 + l15;
    const float bv = bias[gcol];
    #pragma unroll
    for (int i = 0; i < 4; ++i) {
      const int gr = gm0 + m_off + i * 16 + quad * 4;
      #pragma unroll
      for (int r = 0; r < 4; ++r)
        C[(size_t)(gr + r) * 1024 + gcol] = (CT)(acc[i][j][r] + bv);
    }
  }
}

__global__ __launch_bounds__(256) void qkv_gemm_kernel(
    const float* __restrict__ x,
    const float* __restrict__ Wq, const float* __restrict__ bq,
    const float* __restrict__ Wk, const float* __restrict__ bk,
    const float* __restrict__ Wv, const float* __restrict__ bv,
    bf16* Q, bf16* K, bf16* V)
{
  const float* W; const float* bias; bf16* out;
  if (blockIdx.z == 0)      { W = Wq; bias = bq; out = Q; }
  else if (blockIdx.z == 1) { W = Wk; bias = bk; out = K; }
  else                      { W = Wv; bias = bv; out = V; }
  gemm128_body<float, bf16>(x, W, bias, out);
}

__global__ __launch_bounds__(256) void out_gemm_kernel(
    const bf16* __restrict__ ctx, const float* __restrict__ Wo,
    const float* __restrict__ bo, float* __restrict__ out)
{
  gemm128_body<bf16, float>(ctx, Wo, bo, out);
}

// ---------------------------------------------------------------------------
// Flash attention: grid (32 q-tiles, 64 bh). Block = 4 waves, 64 queries.
// Q/K/V in [B*S, 1024] bf16 layout, head slice = columns [h*64, h*64+64).
// ---------------------------------------------------------------------------
__global__ __launch_bounds__(256) void flash_kernel(
    const bf16* Q, const bf16* __restrict__ Kg, const bf16* __restrict__ Vg,
    bf16* ctx)
{
  __shared__ __align__(16) bf16 Ks[64 * 72];      // key-major, padded stride 72
  __shared__ __align__(16) bf16 Vs[64 * 72];      // key-major, padded stride 72
  __shared__ __align__(16) bf16 Vt[64 * 72];      // d-major (transposed)
  __shared__ __align__(16) bf16 Ps[4 * 16 * 72];  // per-wave P tile

  const int tid  = threadIdx.x;
  const int lane = tid & 63;
  const int wave = tid >> 6;
  const int quad = lane >> 4;
  const int l15  = lane & 15;

  const int bh = blockIdx.y;
  const int b  = bh >> 4;
  const int h  = bh & 15;
  const int qt = blockIdx.x;

  const size_t row0 = (size_t)b * 2048;
  const int col0 = h * 64;

  // Q fragments: A-layout m = lane&15, k = quad*8+j (m120 verified); in regs
  const int qs = qt * 64 + wave * 16 + l15;
  const bf16* qp = Q + (row0 + qs) * 1024 + col0 + quad * 8;
  const bf16x8 qf0 = *(const bf16x8*)(qp);        // d 0..31
  const bf16x8 qf1 = *(const bf16x8*)(qp + 32);   // d 32..63

  floatx4 o_acc[4] = {};
  float m_run[4], l_run[4];
  #pragma unroll
  for (int r = 0; r < 4; ++r) { m_run[r] = -1e30f; l_run[r] = 0.0f; }

  const float SC = 0.125f * 1.44269504088896341f;  // 1/sqrt(64) * log2(e)

  for (int kb = 0; kb < 2048 / 64; ++kb) {
    // stage K and V chunk rows into registers (no LDS touch yet)
    bf16x8 kr[2], vr[2];
    int srow[2], scol[2];
    #pragma unroll
    for (int i = 0; i < 2; ++i) {
      int c = i * 256 + tid;
      srow[i] = c >> 3;
      scol[i] = (c & 7) * 8;
      kr[i] = *(const bf16x8*)(Kg + (row0 + kb * 64 + srow[i]) * 1024 + col0 + scol[i]);
      vr[i] = *(const bf16x8*)(Vg + (row0 + kb * 64 + srow[i]) * 1024 + col0 + scol[i]);
    }
    __syncthreads();  // all waves done reading Ks/Vs/Vt/Ps from prev chunk
    #pragma unroll
    for (int i = 0; i < 2; ++i) {
      *(bf16x8*)&Ks[srow[i] * 72 + scol[i]] = kr[i];
      *(bf16x8*)&Vs[srow[i] * 72 + scol[i]] = vr[i];
    }
    __syncthreads();  // Ks/Vs visible

    // transpose V: Vt[d][key] = V[key][d]
    #pragma unroll
    for (int i = 0; i < 2; ++i) {
      int s2 = i * 256 + tid;
      int d = s2 & 63;
      int g = s2 >> 6;
      bf16x8 t;
      #pragma unroll
      for (int j = 0; j < 8; ++j) t[j] = Vs[(g * 8 + j) * 72 + d];
      *(bf16x8*)&Vt[d * 72 + g * 8] = t;
    }

    // Q K^T: 4 key n-tiles x 2 k-steps
    floatx4 sc[4];
    #pragma unroll
    for (int j = 0; j < 4; ++j) {
      int rk = j * 16 + l15;
      bf16x8 k0 = *(const bf16x8*)&Ks[rk * 72 + quad * 8];         // d 0..31
      bf16x8 k1 = *(const bf16x8*)&Ks[rk * 72 + 32 + quad * 8];    // d 32..63
      floatx4 z = {};
      z = MFMA_16x16x32(qf0, k0, z);
      z = MFMA_16x16x32(qf1, k1, z);
      sc[j] = z;
    }

    // online softmax; row m = quad*4 + r, row's 16 cols live across the
    // 16 consecutive lanes of this quad (shfl_xor 1/2/4/8 stays in-group)
    float mloc[4];
    #pragma unroll
    for (int r = 0; r < 4; ++r) {
      #pragma unroll
      for (int j = 0; j < 4; ++j) {
        float s = sc[j][r] * SC;
        s = fminf(fmaxf(s, -1e4f), 1e4f);  // NaN-proofing; inactive for sane data
        sc[j][r] = s;
      }
      mloc[r] = fmaxf(fmaxf(sc[0][r], sc[1][r]), fmaxf(sc[2][r], sc[3][r]));
    }
    #pragma unroll
    for (int off = 1; off < 16; off <<= 1)
      #pragma unroll
      for (int r = 0; r < 4; ++r)
        mloc[r] = fmaxf(mloc[r], __shfl_xor(mloc[r], off, 64));

    float alpha[4], lsum[4];
    #pragma unroll
    for (int r = 0; r < 4; ++r) {
      float mnew = fmaxf(m_run[r], mloc[r]);
      alpha[r] = exp2f(m_run[r] - mnew);
      m_run[r] = mnew;
      lsum[r] = 0.0f;
    }
    #pragma unroll
    for (int j = 0; j < 4; ++j)
      #pragma unroll
      for (int r = 0; r < 4; ++r) {
        float p = exp2f(sc[j][r] - m_run[r]);
        sc[j][r] = p;
        lsum[r] += p;
      }
    #pragma unroll
    for (int off = 1; off < 16; off <<= 1)
      #pragma unroll
      for (int r = 0; r < 4; ++r)
        lsum[r] += __shfl_xor(lsum[r], off, 64);
    #pragma unroll
    for (int r = 0; r < 4; ++r) {
      l_run[r] = l_run[r] * alpha[r] + lsum[r];
      o_acc[0][r] *= alpha[r]; o_acc[1][r] *= alpha[r];
      o_acc[2][r] *= alpha[r]; o_acc[3][r] *= alpha[r];
    }

    // P: C-layout -> LDS -> A-layout (m120's verified transform)
    #pragma unroll
    for (int j = 0; j < 4; ++j)
      #pragma unroll
      for (int r = 0; r < 4; ++r)
        Ps[(wave * 16 + quad * 4 + r) * 72 + j * 16 + l15] = (bf16)sc[j][r];

    __syncthreads();  // Vt (cross-wave) and Ps complete

    // P V: A = P (m=query, k=key), B = V (n=d via Vt rows, k=key contiguous)
    #pragma unroll
    for (int kk = 0; kk < 2; ++kk) {
      bf16x8 pf = *(const bf16x8*)&Ps[(wave * 16 + l15) * 72 + kk * 32 + quad * 8];
      #pragma unroll
      for (int t = 0; t < 4; ++t) {
        bf16x8 vf = *(const bf16x8*)&Vt[(t * 16 + l15) * 72 + kk * 32 + quad * 8];
        o_acc[t] = MFMA_16x16x32(pf, vf, o_acc[t]);
      }
    }
  }

  #pragma unroll
  for (int r = 0; r < 4; ++r) l_run[r] = 1.0f / l_run[r];
  #pragma unroll
  for (int t = 0; t < 4; ++t) {
    #pragma unroll
    for (int r = 0; r < 4; ++r) {
      int srow = qt * 64 + wave * 16 + quad * 4 + r;
      ctx[(row0 + srow) * 1024 + col0 + t * 16 + l15] = (bf16)(o_acc[t][r] * l_run[r]);
    }
  }
}

extern "C" void kernel_launch(void* const* d_in, const int* in_sizes, int n_in,
                              void* d_out, int out_size, void* d_ws, size_t ws_size,
                              hipStream_t stream) {
  (void)in_sizes; (void)n_in; (void)out_size;
  const float* x  = (const float*)d_in[0];
  const float* Wq = (const float*)d_in[1];
  const float* bq = (const float*)d_in[2];
  const float* Wk = (const float*)d_in[3];
  const float* bk = (const float*)d_in[4];
  const float* Wv = (const float*)d_in[5];
  const float* bv = (const float*)d_in[6];
  const float* Wo = (const float*)d_in[7];
  const float* bo = (const float*)d_in[8];
  float* out = (float*)d_out;

  const size_t nElem = (size_t)8192 * 1024;
  bf16* Qw = (bf16*)d_ws;
  bf16* Kw = Qw + nElem;
  bf16* Vw = Kw + nElem;
  // ctx: separate region if workspace allows, else alias onto Q (safe: each
  // flash block reads exactly the Q slice it later writes, before writing it;
  // blocks' slices are disjoint)
  bf16* ctx = (ws_size >= 4 * nElem * sizeof(bf16)) ? (Vw + nElem) : Qw;

  qkv_gemm_kernel<<<dim3(8, 64, 3), 256, 0, stream>>>(x, Wq, bq, Wk, bk, Wv, bv, Qw, Kw, Vw);
  flash_kernel<<<dim3(32, 64, 1), 256, 0, stream>>>(Qw, Kw, Vw, ctx);
  out_gemm_kernel<<<dim3(8, 64, 1), 256, 0, stream>>>(ctx, Wo, bo, out);
}

// Round 4
// 359.433 us; speedup vs baseline: 1.4616x; 1.4616x over previous
//
#include <hip/hip_runtime.h>
#include <hip/hip_bf16.h>

typedef __bf16 bf16;
typedef __attribute__((ext_vector_type(4))) __bf16 bf16x4;
typedef __attribute__((ext_vector_type(8))) __bf16 bf16x8;
typedef __attribute__((ext_vector_type(4))) float floatx4;

#define MFMA_16x16x32(a, b, c) __builtin_amdgcn_mfma_f32_16x16x32_bf16((a), (b), (c), 0, 0, 0)

// load 8 consecutive elements as bf16x8, converting if source is fp32
__device__ __forceinline__ bf16x8 load8(const bf16* p) {
  return *(const bf16x8*)p;
}
__device__ __forceinline__ bf16x8 load8(const float* p) {
  floatx4 a = *(const floatx4*)p;
  floatx4 b = *(const floatx4*)(p + 4);
  bf16x8 r;
  r[0] = (bf16)a[0]; r[1] = (bf16)a[1]; r[2] = (bf16)a[2]; r[3] = (bf16)a[3];
  r[4] = (bf16)b[0]; r[5] = (bf16)b[1]; r[6] = (bf16)b[2]; r[7] = (bf16)b[3];
  return r;
}

// fp32 -> bf16 elementwise cast (x pre-cast so QKV GEMM stages half the bytes)
__global__ __launch_bounds__(256) void cast_kernel(const float* __restrict__ x,
                                                   bf16* __restrict__ xb) {
  int i = (blockIdx.x * 256 + threadIdx.x) * 4;
  floatx4 v = *(const floatx4*)(x + i);
  bf16x4 r;
  r[0] = (bf16)v[0]; r[1] = (bf16)v[1]; r[2] = (bf16)v[2]; r[3] = (bf16)v[3];
  *(bf16x4*)(xb + i) = r;
}

// ---------------------------------------------------------------------------
// GEMM: C[M,N] = A[M,K] @ W[N,K]^T + bias, M=8192, N=1024, K=1024.
// 128x128 tile, BK=64, 256 threads = 4 waves, each wave 64x64 (4x4 MFMA).
// ---------------------------------------------------------------------------
template <typename AT, typename CT>
__device__ __forceinline__ void gemm128_body(
    const AT* __restrict__ A, const float* __restrict__ W,
    const float* __restrict__ bias, CT* __restrict__ C)
{
  constexpr int Kdim = 1024;
  constexpr int LDP = 72;
  __shared__ __align__(16) bf16 As[128 * LDP];
  __shared__ __align__(16) bf16 Bs[128 * LDP];

  const int tid  = threadIdx.x;
  const int lane = tid & 63;
  const int wave = tid >> 6;
  const int quad = lane >> 4;
  const int l15  = lane & 15;

  const int gm0   = blockIdx.y * 128;
  const int gn0   = blockIdx.x * 128;
  const int m_off = (wave >> 1) * 64;
  const int n_off = (wave & 1) * 64;

  floatx4 acc[4][4] = {};

  int srow[4], scol[4];
  #pragma unroll
  for (int i = 0; i < 4; ++i) {
    int c = i * 256 + tid;
    srow[i] = c >> 3;
    scol[i] = (c & 7) * 8;
  }

  for (int kt = 0; kt < Kdim / 64; ++kt) {
    bf16x8 ar[4], br[4];
    #pragma unroll
    for (int i = 0; i < 4; ++i) {
      ar[i] = load8(A + (size_t)(gm0 + srow[i]) * Kdim + kt * 64 + scol[i]);
      br[i] = load8(W + (size_t)(gn0 + srow[i]) * Kdim + kt * 64 + scol[i]);
    }
    __syncthreads();
    #pragma unroll
    for (int i = 0; i < 4; ++i) {
      *(bf16x8*)&As[srow[i] * LDP + scol[i]] = ar[i];
      *(bf16x8*)&Bs[srow[i] * LDP + scol[i]] = br[i];
    }
    __syncthreads();

    #pragma unroll
    for (int kk = 0; kk < 2; ++kk) {
      bf16x8 af[4], bfr[4];
      #pragma unroll
      for (int i = 0; i < 4; ++i) {
        af[i]  = *(const bf16x8*)&As[(m_off + i * 16 + l15) * LDP + (kk * 4 + quad) * 8];
        bfr[i] = *(const bf16x8*)&Bs[(n_off + i * 16 + l15) * LDP + (kk * 4 + quad) * 8];
      }
      #pragma unroll
      for (int i = 0; i < 4; ++i)
        #pragma unroll
        for (int j = 0; j < 4; ++j)
          acc[i][j] = MFMA_16x16x32(af[i], bfr[j], acc[i][j]);
    }
  }

  #pragma unroll
  for (int j = 0; j < 4; ++j) {
    const int gcol = gn0 + n_off + j * 16 + l15;
    const float bv = bias[gcol];
    #pragma unroll
    for (int i = 0; i < 4; ++i) {
      const int gr = gm0 + m_off + i * 16 + quad * 4;
      #pragma unroll
      for (int r = 0; r < 4; ++r)
        C[(size_t)(gr + r) * 1024 + gcol] = (CT)(acc[i][j][r] + bv);
    }
  }
}

template <typename AT>
__global__ __launch_bounds__(256) void qkv_gemm_kernel(
    const AT* __restrict__ x,
    const float* __restrict__ Wq, const float* __restrict__ bq,
    const float* __restrict__ Wk, const float* __restrict__ bk,
    const float* __restrict__ Wv, const float* __restrict__ bv,
    bf16* Q, bf16* K, bf16* V)
{
  const float* W; const float* bias; bf16* out;
  if (blockIdx.z == 0)      { W = Wq; bias = bq; out = Q; }
  else if (blockIdx.z == 1) { W = Wk; bias = bk; out = K; }
  else                      { W = Wv; bias = bv; out = V; }
  gemm128_body<AT, bf16>(x, W, bias, out);
}

__global__ __launch_bounds__(256) void out_gemm_kernel(
    const bf16* __restrict__ ctx, const float* __restrict__ Wo,
    const float* __restrict__ bo, float* __restrict__ out)
{
  gemm128_body<bf16, float>(ctx, Wo, bo, out);
}

// ---------------------------------------------------------------------------
// Flash attention v2: grid (16 q-tiles, 64 bh). Block = 8 waves (512 thr),
// 128 queries/block, 16 queries/wave. No-max softmax (scores analytically
// bounded; exp2 guard at +60), deferred l-reduction.
// ---------------------------------------------------------------------------
__global__ __launch_bounds__(512) void flash_kernel(
    const bf16* Q, const bf16* __restrict__ Kg, const bf16* __restrict__ Vg,
    bf16* ctx)
{
  __shared__ __align__(16) bf16 Ks[64 * 72];      // key-major, padded 72
  __shared__ __align__(16) bf16 Vs[64 * 72];      // key-major
  __shared__ __align__(16) bf16 Vt[64 * 72];      // d-major (transposed)
  __shared__ __align__(16) bf16 Ps[8 * 16 * 72];  // per-wave P tile

  const int tid  = threadIdx.x;
  const int lane = tid & 63;
  const int wave = tid >> 6;
  const int quad = lane >> 4;
  const int l15  = lane & 15;

  const int bh = blockIdx.y;
  const int b  = bh >> 4;
  const int h  = bh & 15;
  const int qt = blockIdx.x;

  const size_t row0 = (size_t)b * 2048;
  const int col0 = h * 64;

  // Q fragments: A-layout m = lane&15, k = quad*8+j; held in regs all kernel
  const int qs = qt * 128 + wave * 16 + l15;
  const bf16* qp = Q + (row0 + qs) * 1024 + col0 + quad * 8;
  const bf16x8 qf0 = *(const bf16x8*)(qp);        // d 0..31
  const bf16x8 qf1 = *(const bf16x8*)(qp + 32);   // d 32..63

  floatx4 o_acc[4] = {};
  float l_part[4] = {0.0f, 0.0f, 0.0f, 0.0f};

  const float SC = 0.125f * 1.44269504088896341f;  // 1/sqrt(64) * log2(e)

  // staging assignment: one K row-piece + one V row-piece per thread
  const int srow = tid >> 3;        // key row 0..63
  const int scol = (tid & 7) * 8;   // d 0,8,...,56
  const bf16* kptr = Kg + (row0 + srow) * 1024 + col0 + scol;
  const bf16* vptr = Vg + (row0 + srow) * 1024 + col0 + scol;

  // transpose assignment
  const int td = tid & 63;          // d
  const int tg = tid >> 6;          // key group 0..7

  for (int kb = 0; kb < 32; ++kb) {
    bf16x8 kr = *(const bf16x8*)kptr;
    bf16x8 vr = *(const bf16x8*)vptr;
    kptr += 64 * 1024;
    vptr += 64 * 1024;

    __syncthreads();  // all waves done reading Ks/Vt from previous chunk
    *(bf16x8*)&Ks[srow * 72 + scol] = kr;
    *(bf16x8*)&Vs[srow * 72 + scol] = vr;
    __syncthreads();  // Ks/Vs visible

    // transpose V: Vt[d][key] = Vs[key][d]
    {
      bf16x8 t;
      #pragma unroll
      for (int j = 0; j < 8; ++j) t[j] = Vs[(tg * 8 + j) * 72 + td];
      *(bf16x8*)&Vt[td * 72 + tg * 8] = t;
    }

    // Q K^T: 4 key n-tiles x 2 k-steps = 8 MFMA
    floatx4 sc[4];
    #pragma unroll
    for (int j = 0; j < 4; ++j) {
      int rk = j * 16 + l15;
      bf16x8 k0 = *(const bf16x8*)&Ks[rk * 72 + quad * 8];
      bf16x8 k1 = *(const bf16x8*)&Ks[rk * 72 + 32 + quad * 8];
      floatx4 z = {};
      z = MFMA_16x16x32(qf0, k0, z);
      z = MFMA_16x16x32(qf1, k1, z);
      sc[j] = z;
    }

    // no-max softmax: p = exp2(s*SC), accumulate per-lane l partials
    #pragma unroll
    for (int j = 0; j < 4; ++j)
      #pragma unroll
      for (int r = 0; r < 4; ++r) {
        float p = exp2f(fminf(sc[j][r] * SC, 60.0f));
        sc[j][r] = p;
        l_part[r] += p;
      }

    // P: C-layout -> LDS -> A-layout (per-wave region)
    #pragma unroll
    for (int j = 0; j < 4; ++j)
      #pragma unroll
      for (int r = 0; r < 4; ++r)
        Ps[(wave * 16 + quad * 4 + r) * 72 + j * 16 + l15] = (bf16)sc[j][r];

    __syncthreads();  // Vt (cross-wave) ready; Ps writes drained

    // P V: 2 k-steps x 4 d-tiles = 8 MFMA
    #pragma unroll
    for (int kk = 0; kk < 2; ++kk) {
      bf16x8 pf = *(const bf16x8*)&Ps[(wave * 16 + l15) * 72 + kk * 32 + quad * 8];
      #pragma unroll
      for (int t = 0; t < 4; ++t) {
        bf16x8 vf = *(const bf16x8*)&Vt[(t * 16 + l15) * 72 + kk * 32 + quad * 8];
        o_acc[t] = MFMA_16x16x32(pf, vf, o_acc[t]);
      }
    }
  }

  // final l reduction over the 16 lanes holding each row's columns
  #pragma unroll
  for (int off = 1; off < 16; off <<= 1)
    #pragma unroll
    for (int r = 0; r < 4; ++r)
      l_part[r] += __shfl_xor(l_part[r], off, 64);
  #pragma unroll
  for (int r = 0; r < 4; ++r) l_part[r] = 1.0f / l_part[r];

  #pragma unroll
  for (int t = 0; t < 4; ++t)
    #pragma unroll
    for (int r = 0; r < 4; ++r) {
      int srow2 = qt * 128 + wave * 16 + quad * 4 + r;
      ctx[(row0 + srow2) * 1024 + col0 + t * 16 + l15] = (bf16)(o_acc[t][r] * l_part[r]);
    }
}

extern "C" void kernel_launch(void* const* d_in, const int* in_sizes, int n_in,
                              void* d_out, int out_size, void* d_ws, size_t ws_size,
                              hipStream_t stream) {
  (void)in_sizes; (void)n_in; (void)out_size;
  const float* x  = (const float*)d_in[0];
  const float* Wq = (const float*)d_in[1];
  const float* bq = (const float*)d_in[2];
  const float* Wk = (const float*)d_in[3];
  const float* bk = (const float*)d_in[4];
  const float* Wv = (const float*)d_in[5];
  const float* bv = (const float*)d_in[6];
  const float* Wo = (const float*)d_in[7];
  const float* bo = (const float*)d_in[8];
  float* out = (float*)d_out;

  const size_t nElem = (size_t)8192 * 1024;
  bf16* Qw = (bf16*)d_ws;
  bf16* Kw = Qw + nElem;
  bf16* Vw = Kw + nElem;
  const bool haveCtx = ws_size >= 4 * nElem * sizeof(bf16);
  const bool haveXb  = ws_size >= 5 * nElem * sizeof(bf16);
  bf16* ctx = haveCtx ? (Vw + nElem) : Qw;
  bf16* xb  = haveXb ? (Vw + 2 * nElem) : nullptr;

  if (haveXb) {
    cast_kernel<<<dim3(nElem / 1024), 256, 0, stream>>>(x, xb);
    qkv_gemm_kernel<bf16><<<dim3(8, 64, 3), 256, 0, stream>>>(
        xb, Wq, bq, Wk, bk, Wv, bv, Qw, Kw, Vw);
  } else {
    qkv_gemm_kernel<float><<<dim3(8, 64, 3), 256, 0, stream>>>(
        x, Wq, bq, Wk, bk, Wv, bv, Qw, Kw, Vw);
  }
  flash_kernel<<<dim3(16, 64, 1), 512, 0, stream>>>(Qw, Kw, Vw, ctx);
  out_gemm_kernel<<<dim3(8, 64, 1), 256, 0, stream>>>(ctx, Wo, bo, out);
}

// Round 5
// 338.458 us; speedup vs baseline: 1.5522x; 1.0620x over previous
//
#include <hip/hip_runtime.h>
#include <hip/hip_bf16.h>

typedef __bf16 bf16;
typedef __attribute__((ext_vector_type(4))) __bf16 bf16x4;
typedef __attribute__((ext_vector_type(8))) __bf16 bf16x8;
typedef __attribute__((ext_vector_type(4))) float floatx4;

#define MFMA_16x16x32(a, b, c) __builtin_amdgcn_mfma_f32_16x16x32_bf16((a), (b), (c), 0, 0, 0)

__device__ __forceinline__ void async_lds16(const bf16* g, bf16* lds) {
  __builtin_amdgcn_global_load_lds(
      (__attribute__((address_space(1))) void*)(g),
      (__attribute__((address_space(3))) void*)(lds),
      16, 0, 0);
}

// generic fp32 -> bf16 cast, 8 elems/thread
__global__ __launch_bounds__(256) void cast_kernel(const float* __restrict__ src,
                                                   bf16* __restrict__ dst, int n) {
  int i = (blockIdx.x * 256 + threadIdx.x) * 8;
  if (i >= n) return;
  floatx4 a = *(const floatx4*)(src + i);
  floatx4 b = *(const floatx4*)(src + i + 4);
  bf16x8 r;
  r[0] = (bf16)a[0]; r[1] = (bf16)a[1]; r[2] = (bf16)a[2]; r[3] = (bf16)a[3];
  r[4] = (bf16)b[0]; r[5] = (bf16)b[1]; r[6] = (bf16)b[2]; r[7] = (bf16)b[3];
  *(bf16x8*)(dst + i) = r;
}

// ---------------------------------------------------------------------------
// MAIN PATH: pure-bf16 GEMM, m97-style global_load_lds staging, XOR-swizzled
// 16B cells (LDS cell k of row r holds source cell k^(r&7) -> <=2-way bank
// aliasing, free per m136). 128x128 tile, BK=64, 4 waves, 4x4 MFMA per wave.
// VT=true: write C transposed per head: Vt[(b*16+h)*64+dh][s] (b64 packed).
// ---------------------------------------------------------------------------
template <typename CT, bool VT>
__device__ __forceinline__ void gemm_async_body(
    const bf16* __restrict__ A, const bf16* __restrict__ W,
    const float* __restrict__ bias, CT* __restrict__ C)
{
  __shared__ __align__(16) bf16 As[128 * 64];
  __shared__ __align__(16) bf16 Bs[128 * 64];

  const int tid  = threadIdx.x;
  const int lane = tid & 63;
  const int wave = tid >> 6;
  const int quad = lane >> 4;
  const int l15  = lane & 15;

  const int gm0   = blockIdx.y * 128;
  const int gn0   = blockIdx.x * 128;
  const int m_off = (wave >> 1) * 64;
  const int n_off = (wave & 1) * 64;

  floatx4 acc[4][4] = {};

  const bf16* ap[4];
  const bf16* wp[4];
  #pragma unroll
  for (int i = 0; i < 4; ++i) {
    int c = i * 256 + tid;
    int srow = c >> 3;                 // tile row 0..127
    int ksw  = (c & 7) ^ (srow & 7);   // swizzled source 16B cell
    ap[i] = A + (size_t)(gm0 + srow) * 1024 + ksw * 8;
    wp[i] = W + (size_t)(gn0 + srow) * 1024 + ksw * 8;
  }

  for (int kt = 0; kt < 16; ++kt) {
    __syncthreads();  // previous iteration's fragment reads complete
    #pragma unroll
    for (int i = 0; i < 4; ++i) {
      int c = i * 256 + tid;
      async_lds16(ap[i], &As[c * 8]);
      async_lds16(wp[i], &Bs[c * 8]);
      ap[i] += 64; wp[i] += 64;
    }
    __syncthreads();  // vmcnt drained -> tiles visible

    #pragma unroll
    for (int kk = 0; kk < 2; ++kk) {
      bf16x8 af[4], bfr[4];
      #pragma unroll
      for (int i = 0; i < 4; ++i) {
        int rm = m_off + i * 16 + l15;
        af[i]  = *(const bf16x8*)&As[rm * 64 + (((kk * 4 + quad) ^ (rm & 7)) * 8)];
        int rn = n_off + i * 16 + l15;
        bfr[i] = *(const bf16x8*)&Bs[rn * 64 + (((kk * 4 + quad) ^ (rn & 7)) * 8)];
      }
      #pragma unroll
      for (int i = 0; i < 4; ++i)
        #pragma unroll
        for (int j = 0; j < 4; ++j)
          acc[i][j] = MFMA_16x16x32(af[i], bfr[j], acc[i][j]);
    }
  }

  // epilogue: C/D layout col = lane&15, row = quad*4 + reg
  #pragma unroll
  for (int j = 0; j < 4; ++j) {
    const int gcol = gn0 + n_off + j * 16 + l15;
    const float bv = bias[gcol];
    #pragma unroll
    for (int i = 0; i < 4; ++i) {
      const int gr = gm0 + m_off + i * 16 + quad * 4;
      if constexpr (VT) {
        // transposed-per-head: token gr+r -> (b, s); col -> (h, dh)
        const int h  = gcol >> 6;
        const int dh = gcol & 63;
        const size_t base =
            (((size_t)(gr >> 11) * 16 + h) * 64 + dh) * 2048 + (gr & 2047);
        bf16x4 pk;
        #pragma unroll
        for (int r = 0; r < 4; ++r) pk[r] = (bf16)(acc[i][j][r] + bv);
        *(bf16x4*)&C[base] = pk;   // 4 consecutive s -> one b64 store
      } else {
        #pragma unroll
        for (int r = 0; r < 4; ++r)
          C[(size_t)(gr + r) * 1024 + gcol] = (CT)(acc[i][j][r] + bv);
      }
    }
  }
}

__global__ __launch_bounds__(256) void qk_gemm_async(
    const bf16* __restrict__ xb,
    const bf16* __restrict__ Wqb, const float* __restrict__ bq,
    const bf16* __restrict__ Wkb, const float* __restrict__ bk,
    bf16* Q, bf16* K)
{
  const bf16* W = blockIdx.z ? Wkb : Wqb;
  const float* bias = blockIdx.z ? bk : bq;
  bf16* out = blockIdx.z ? K : Q;
  gemm_async_body<bf16, false>(xb, W, bias, out);
}

__global__ __launch_bounds__(256) void v_gemm_async(
    const bf16* __restrict__ xb, const bf16* __restrict__ Wvb,
    const float* __restrict__ bv, bf16* __restrict__ Vt)
{
  gemm_async_body<bf16, true>(xb, Wvb, bv, Vt);
}

__global__ __launch_bounds__(256) void o_gemm_async(
    const bf16* __restrict__ ctx, const bf16* __restrict__ Wob,
    const float* __restrict__ bo, float* __restrict__ out)
{
  gemm_async_body<float, false>(ctx, Wob, bo, out);
}

// ---------------------------------------------------------------------------
// Flash v3: grid (16 q-tiles, 64 bh), 512 threads = 8 waves, 128 queries.
// K staged from [token][1024]; V staged PRE-TRANSPOSED from Vt[(bh)*64+dh][s]
// (no in-kernel transpose). Both via global_load_lds w/ XOR swizzle.
// No-max softmax; Ps is wave-private (no barrier). 2 barriers/iter.
// ---------------------------------------------------------------------------
__global__ __launch_bounds__(512) void flash3_kernel(
    const bf16* __restrict__ Q, const bf16* __restrict__ Kg,
    const bf16* __restrict__ Vtg, bf16* __restrict__ ctx)
{
  __shared__ __align__(16) bf16 Ks[64 * 64];    // [key][d] swizzled cells
  __shared__ __align__(16) bf16 Vts[64 * 64];   // [d][key] swizzled cells
  __shared__ __align__(16) bf16 Ps[8 * 16 * 72];

  const int tid  = threadIdx.x;
  const int lane = tid & 63;
  const int wave = tid >> 6;
  const int quad = lane >> 4;
  const int l15  = lane & 15;

  const int bh = blockIdx.y;
  const int b  = bh >> 4;
  const int h  = bh & 15;
  const int qt = blockIdx.x;

  const size_t row0 = (size_t)b * 2048;
  const int col0 = h * 64;

  // Q fragments in regs (A-layout m=lane&15, k=quad*8+j)
  const int qs = qt * 128 + wave * 16 + l15;
  const bf16* qp = Q + (row0 + qs) * 1024 + col0 + quad * 8;
  const bf16x8 qf0 = *(const bf16x8*)(qp);
  const bf16x8 qf1 = *(const bf16x8*)(qp + 32);

  floatx4 o_acc[4] = {};
  float l_part[4] = {0.0f, 0.0f, 0.0f, 0.0f};
  const float SC = 0.125f * 1.44269504088896341f;  // 1/sqrt(64) * log2(e)

  // staging: thread -> (row srow, swizzled cell)
  const int srow = tid >> 3;
  const int ksw  = (tid & 7) ^ (srow & 7);
  const bf16* kp = Kg + (row0 + srow) * 1024 + col0 + ksw * 8;
  const bf16* vp = Vtg + ((size_t)bh * 64 + srow) * 2048 + ksw * 8;
  bf16* const ksd = &Ks[tid * 8];
  bf16* const vtd = &Vts[tid * 8];

  for (int kb = 0; kb < 32; ++kb) {
    __syncthreads();  // all waves done reading Ks/Vts of previous chunk
    async_lds16(kp, ksd);
    async_lds16(vp, vtd);
    kp += 64 * 1024;
    vp += 64;
    __syncthreads();  // vmcnt drained -> Ks/Vts visible

    // Q K^T: 4 key-tiles x 2 k-steps = 8 MFMA
    floatx4 sc[4];
    #pragma unroll
    for (int j = 0; j < 4; ++j) {
      int rk = j * 16 + l15;
      bf16x8 k0 = *(const bf16x8*)&Ks[rk * 64 + ((quad ^ (rk & 7)) * 8)];
      bf16x8 k1 = *(const bf16x8*)&Ks[rk * 64 + (((4 + quad) ^ (rk & 7)) * 8)];
      floatx4 z = {};
      z = MFMA_16x16x32(qf0, k0, z);
      z = MFMA_16x16x32(qf1, k1, z);
      sc[j] = z;
    }

    // no-max softmax with deferred l-reduction
    #pragma unroll
    for (int j = 0; j < 4; ++j)
      #pragma unroll
      for (int r = 0; r < 4; ++r) {
        float p = exp2f(fminf(sc[j][r] * SC, 60.0f));
        sc[j][r] = p;
        l_part[r] += p;
      }

    // P: C-layout -> LDS -> A-layout (wave-private region; no barrier needed)
    #pragma unroll
    for (int j = 0; j < 4; ++j)
      #pragma unroll
      for (int r = 0; r < 4; ++r)
        Ps[(wave * 16 + quad * 4 + r) * 72 + j * 16 + l15] = (bf16)sc[j][r];

    // P V: 2 k-steps x 4 d-tiles = 8 MFMA
    #pragma unroll
    for (int kk = 0; kk < 2; ++kk) {
      bf16x8 pf = *(const bf16x8*)&Ps[(wave * 16 + l15) * 72 + kk * 32 + quad * 8];
      #pragma unroll
      for (int t = 0; t < 4; ++t) {
        int rd = t * 16 + l15;
        bf16x8 vf = *(const bf16x8*)&Vts[rd * 64 + (((kk * 4 + quad) ^ (rd & 7)) * 8)];
        o_acc[t] = MFMA_16x16x32(pf, vf, o_acc[t]);
      }
    }
  }

  #pragma unroll
  for (int off = 1; off < 16; off <<= 1)
    #pragma unroll
    for (int r = 0; r < 4; ++r)
      l_part[r] += __shfl_xor(l_part[r], off, 64);
  #pragma unroll
  for (int r = 0; r < 4; ++r) l_part[r] = 1.0f / l_part[r];

  #pragma unroll
  for (int t = 0; t < 4; ++t)
    #pragma unroll
    for (int r = 0; r < 4; ++r) {
      int srow2 = qt * 128 + wave * 16 + quad * 4 + r;
      ctx[(row0 + srow2) * 1024 + col0 + t * 16 + l15] = (bf16)(o_acc[t][r] * l_part[r]);
    }
}

// ---------------------------------------------------------------------------
// FALLBACK PATH (round-4, used only if workspace < 88 MB)
// ---------------------------------------------------------------------------
__device__ __forceinline__ bf16x8 load8(const bf16* p) { return *(const bf16x8*)p; }
__device__ __forceinline__ bf16x8 load8(const float* p) {
  floatx4 a = *(const floatx4*)p;
  floatx4 b = *(const floatx4*)(p + 4);
  bf16x8 r;
  r[0] = (bf16)a[0]; r[1] = (bf16)a[1]; r[2] = (bf16)a[2]; r[3] = (bf16)a[3];
  r[4] = (bf16)b[0]; r[5] = (bf16)b[1]; r[6] = (bf16)b[2]; r[7] = (bf16)b[3];
  return r;
}

template <typename AT, typename CT>
__device__ __forceinline__ void gemm128_body_fb(
    const AT* __restrict__ A, const float* __restrict__ W,
    const float* __restrict__ bias, CT* __restrict__ C)
{
  constexpr int LDP = 72;
  __shared__ __align__(16) bf16 As[128 * LDP];
  __shared__ __align__(16) bf16 Bs[128 * LDP];
  const int tid = threadIdx.x, lane = tid & 63, wave = tid >> 6;
  const int quad = lane >> 4, l15 = lane & 15;
  const int gm0 = blockIdx.y * 128, gn0 = blockIdx.x * 128;
  const int m_off = (wave >> 1) * 64, n_off = (wave & 1) * 64;
  floatx4 acc[4][4] = {};
  int srow[4], scol[4];
  #pragma unroll
  for (int i = 0; i < 4; ++i) {
    int c = i * 256 + tid;
    srow[i] = c >> 3; scol[i] = (c & 7) * 8;
  }
  for (int kt = 0; kt < 16; ++kt) {
    bf16x8 ar[4], br[4];
    #pragma unroll
    for (int i = 0; i < 4; ++i) {
      ar[i] = load8(A + (size_t)(gm0 + srow[i]) * 1024 + kt * 64 + scol[i]);
      br[i] = load8(W + (size_t)(gn0 + srow[i]) * 1024 + kt * 64 + scol[i]);
    }
    __syncthreads();
    #pragma unroll
    for (int i = 0; i < 4; ++i) {
      *(bf16x8*)&As[srow[i] * LDP + scol[i]] = ar[i];
      *(bf16x8*)&Bs[srow[i] * LDP + scol[i]] = br[i];
    }
    __syncthreads();
    #pragma unroll
    for (int kk = 0; kk < 2; ++kk) {
      bf16x8 af[4], bfr[4];
      #pragma unroll
      for (int i = 0; i < 4; ++i) {
        af[i]  = *(const bf16x8*)&As[(m_off + i * 16 + l15) * LDP + (kk * 4 + quad) * 8];
        bfr[i] = *(const bf16x8*)&Bs[(n_off + i * 16 + l15) * LDP + (kk * 4 + quad) * 8];
      }
      #pragma unroll
      for (int i = 0; i < 4; ++i)
        #pragma unroll
        for (int j = 0; j < 4; ++j)
          acc[i][j] = MFMA_16x16x32(af[i], bfr[j], acc[i][j]);
    }
  }
  #pragma unroll
  for (int j = 0; j < 4; ++j) {
    const int gcol = gn0 + n_off + j * 16 + l15;
    const float bv = bias[gcol];
    #pragma unroll
    for (int i = 0; i < 4; ++i) {
      const int gr = gm0 + m_off + i * 16 + quad * 4;
      #pragma unroll
      for (int r = 0; r < 4; ++r)
        C[(size_t)(gr + r) * 1024 + gcol] = (CT)(acc[i][j][r] + bv);
    }
  }
}

__global__ __launch_bounds__(256) void qkv_gemm_fb(
    const float* __restrict__ x,
    const float* __restrict__ Wq, const float* __restrict__ bq,
    const float* __restrict__ Wk, const float* __restrict__ bk,
    const float* __restrict__ Wv, const float* __restrict__ bv,
    bf16* Q, bf16* K, bf16* V)
{
  const float* W; const float* bias; bf16* out;
  if (blockIdx.z == 0)      { W = Wq; bias = bq; out = Q; }
  else if (blockIdx.z == 1) { W = Wk; bias = bk; out = K; }
  else                      { W = Wv; bias = bv; out = V; }
  gemm128_body_fb<float, bf16>(x, W, bias, out);
}

__global__ __launch_bounds__(256) void out_gemm_fb(
    const bf16* __restrict__ ctx, const float* __restrict__ Wo,
    const float* __restrict__ bo, float* __restrict__ out)
{
  gemm128_body_fb<bf16, float>(ctx, Wo, bo, out);
}

__global__ __launch_bounds__(512) void flash_fb(
    const bf16* Q, const bf16* __restrict__ Kg, const bf16* __restrict__ Vg,
    bf16* ctx)
{
  __shared__ __align__(16) bf16 Ks[64 * 72];
  __shared__ __align__(16) bf16 Vs[64 * 72];
  __shared__ __align__(16) bf16 Vt[64 * 72];
  __shared__ __align__(16) bf16 Ps[8 * 16 * 72];
  const int tid = threadIdx.x, lane = tid & 63, wave = tid >> 6;
  const int quad = lane >> 4, l15 = lane & 15;
  const int bh = blockIdx.y, b = bh >> 4, h = bh & 15, qt = blockIdx.x;
  const size_t row0 = (size_t)b * 2048;
  const int col0 = h * 64;
  const int qs = qt * 128 + wave * 16 + l15;
  const bf16* qp = Q + (row0 + qs) * 1024 + col0 + quad * 8;
  const bf16x8 qf0 = *(const bf16x8*)(qp);
  const bf16x8 qf1 = *(const bf16x8*)(qp + 32);
  floatx4 o_acc[4] = {};
  float l_part[4] = {0.0f, 0.0f, 0.0f, 0.0f};
  const float SC = 0.125f * 1.44269504088896341f;
  const int srow = tid >> 3, scol = (tid & 7) * 8;
  const bf16* kptr = Kg + (row0 + srow) * 1024 + col0 + scol;
  const bf16* vptr = Vg + (row0 + srow) * 1024 + col0 + scol;
  const int td = tid & 63, tg = tid >> 6;
  for (int kb = 0; kb < 32; ++kb) {
    bf16x8 kr = *(const bf16x8*)kptr;
    bf16x8 vr = *(const bf16x8*)vptr;
    kptr += 64 * 1024; vptr += 64 * 1024;
    __syncthreads();
    *(bf16x8*)&Ks[srow * 72 + scol] = kr;
    *(bf16x8*)&Vs[srow * 72 + scol] = vr;
    __syncthreads();
    {
      bf16x8 t;
      #pragma unroll
      for (int j = 0; j < 8; ++j) t[j] = Vs[(tg * 8 + j) * 72 + td];
      *(bf16x8*)&Vt[td * 72 + tg * 8] = t;
    }
    floatx4 sc[4];
    #pragma unroll
    for (int j = 0; j < 4; ++j) {
      int rk = j * 16 + l15;
      bf16x8 k0 = *(const bf16x8*)&Ks[rk * 72 + quad * 8];
      bf16x8 k1 = *(const bf16x8*)&Ks[rk * 72 + 32 + quad * 8];
      floatx4 z = {};
      z = MFMA_16x16x32(qf0, k0, z);
      z = MFMA_16x16x32(qf1, k1, z);
      sc[j] = z;
    }
    #pragma unroll
    for (int j = 0; j < 4; ++j)
      #pragma unroll
      for (int r = 0; r < 4; ++r) {
        float p = exp2f(fminf(sc[j][r] * SC, 60.0f));
        sc[j][r] = p;
        l_part[r] += p;
      }
    #pragma unroll
    for (int j = 0; j < 4; ++j)
      #pragma unroll
      for (int r = 0; r < 4; ++r)
        Ps[(wave * 16 + quad * 4 + r) * 72 + j * 16 + l15] = (bf16)sc[j][r];
    __syncthreads();
    #pragma unroll
    for (int kk = 0; kk < 2; ++kk) {
      bf16x8 pf = *(const bf16x8*)&Ps[(wave * 16 + l15) * 72 + kk * 32 + quad * 8];
      #pragma unroll
      for (int t = 0; t < 4; ++t) {
        bf16x8 vf = *(const bf16x8*)&Vt[(t * 16 + l15) * 72 + kk * 32 + quad * 8];
        o_acc[t] = MFMA_16x16x32(pf, vf, o_acc[t]);
      }
    }
  }
  #pragma unroll
  for (int off = 1; off < 16; off <<= 1)
    #pragma unroll
    for (int r = 0; r < 4; ++r)
      l_part[r] += __shfl_xor(l_part[r], off, 64);
  #pragma unroll
  for (int r = 0; r < 4; ++r) l_part[r] = 1.0f / l_part[r];
  #pragma unroll
  for (int t = 0; t < 4; ++t)
    #pragma unroll
    for (int r = 0; r < 4; ++r) {
      int srow2 = qt * 128 + wave * 16 + quad * 4 + r;
      ctx[(row0 + srow2) * 1024 + col0 + t * 16 + l15] = (bf16)(o_acc[t][r] * l_part[r]);
    }
}

extern "C" void kernel_launch(void* const* d_in, const int* in_sizes, int n_in,
                              void* d_out, int out_size, void* d_ws, size_t ws_size,
                              hipStream_t stream) {
  (void)in_sizes; (void)n_in; (void)out_size;
  const float* x  = (const float*)d_in[0];
  const float* Wq = (const float*)d_in[1];
  const float* bq = (const float*)d_in[2];
  const float* Wk = (const float*)d_in[3];
  const float* bk = (const float*)d_in[4];
  const float* Wv = (const float*)d_in[5];
  const float* bv = (const float*)d_in[6];
  const float* Wo = (const float*)d_in[7];
  const float* bo = (const float*)d_in[8];
  float* out = (float*)d_out;

  const size_t nE = (size_t)8192 * 1024;   // 8M elems per activation tensor
  const size_t wE = (size_t)1024 * 1024;   // 1M elems per weight
  const size_t need = (5 * nE + 4 * wE) * sizeof(bf16);  // ~88 MB

  if (ws_size >= need) {
    bf16* Qw   = (bf16*)d_ws;
    bf16* Kw   = Qw + nE;
    bf16* Vtw  = Kw + nE;
    bf16* ctxw = Vtw + nE;
    bf16* xb   = ctxw + nE;
    bf16* Wqb  = xb + nE;
    bf16* Wkb  = Wqb + wE;
    bf16* Wvb  = Wkb + wE;
    bf16* Wob  = Wvb + wE;

    cast_kernel<<<dim3(4096), 256, 0, stream>>>(x, xb, (int)nE);
    cast_kernel<<<dim3(512), 256, 0, stream>>>(Wq, Wqb, (int)wE);
    cast_kernel<<<dim3(512), 256, 0, stream>>>(Wk, Wkb, (int)wE);
    cast_kernel<<<dim3(512), 256, 0, stream>>>(Wv, Wvb, (int)wE);
    cast_kernel<<<dim3(512), 256, 0, stream>>>(Wo, Wob, (int)wE);

    qk_gemm_async<<<dim3(8, 64, 2), 256, 0, stream>>>(xb, Wqb, bq, Wkb, bk, Qw, Kw);
    v_gemm_async<<<dim3(8, 64), 256, 0, stream>>>(xb, Wvb, bv, Vtw);
    flash3_kernel<<<dim3(16, 64), 512, 0, stream>>>(Qw, Kw, Vtw, ctxw);
    o_gemm_async<<<dim3(8, 64), 256, 0, stream>>>(ctxw, Wob, bo, out);
  } else {
    bf16* Qw = (bf16*)d_ws;
    bf16* Kw = Qw + nE;
    bf16* Vw = Kw + nE;
    bf16* ctx = (ws_size >= 4 * nE * sizeof(bf16)) ? (Vw + nE) : Qw;
    qkv_gemm_fb<<<dim3(8, 64, 3), 256, 0, stream>>>(x, Wq, bq, Wk, bk, Wv, bv, Qw, Kw, Vw);
    flash_fb<<<dim3(16, 64), 512, 0, stream>>>(Qw, Kw, Vw, ctx);
    out_gemm_fb<<<dim3(8, 64), 256, 0, stream>>>(ctx, Wo, bo, out);
  }
}